// Round 4
// baseline (653.608 us; speedup 1.0000x reference)
//
#include <hip/hip_runtime.h>

// Problem constants (fixed by the reference)
#define NN 200000   // nodes
#define CC 256      // channels
#define NG 512      // graphs/segments

typedef __attribute__((ext_vector_type(8))) __bf16 bf16x8;
typedef __attribute__((ext_vector_type(16))) float f32x16;

__device__ __forceinline__ unsigned short f2bf(float f) {
  union { float f; unsigned u; } v; v.f = f;
  unsigned u = v.u;
  u += 0x7fffu + ((u >> 16) & 1u);   // RNE
  return (unsigned short)(u >> 16);
}
__device__ __forceinline__ unsigned pack2(float a, float b) {
  return (unsigned)f2bf(a) | ((unsigned)f2bf(b) << 16);
}
__device__ __forceinline__ float bflo(unsigned u){ union{unsigned u; float f;} x; x.u = u << 16; return x.f; }
__device__ __forceinline__ float bfhi(unsigned u){ union{unsigned u; float f;} x; x.u = u & 0xffff0000u; return x.f; }

// ---------------------------------------------------------------------------
// K0: prep all weights into 32x32x16 MFMA *A-operand* fragment order for the
// transposed GEMM  C^T[dim][node] = W^T[dim][k] * x^T[k][node].
//  Wall slice s (16 KB each): A[row r = (s%8)*32 + (l&31)][k = ks*16+(l>>5)*8+j]
//    = W[k*256 + c].   Slices: 0-7 Wv, 8-15 Wk, 16-23 Wq, 24-31 Wo.
//  flat idx = s*8192 + ks*512 + l*8 + j
// ---------------------------------------------------------------------------
__global__ __launch_bounds__(256) void prep_kernel(
    const float* __restrict__ Wq, const float* __restrict__ Wk,
    const float* __restrict__ Wv, const float* __restrict__ Wo,
    unsigned short* __restrict__ Wall) {
  int idx = blockIdx.x * 256 + threadIdx.x;     // 0..262143
  int s = idx >> 13;
  int inner = idx & 8191;
  int ks = inner >> 9;
  int l = (inner >> 3) & 63;
  int j = inner & 7;
  int r = l & 31, hi5 = l >> 5;
  int k = ks * 16 + hi5 * 8 + j;
  const float* W;
  int c;
  if (s < 8)       { W = Wv; c = s * 32 + r; }
  else if (s < 16) { W = Wk; c = (s - 8) * 32 + r; }
  else if (s < 24) { W = Wq; c = (s - 16) * 32 + r; }
  else             { W = Wo; c = (s - 24) * 32 + r; }
  Wall[idx] = f2bf(W[k * 256 + c]);
}

// ---------------------------------------------------------------------------
// K1: segment boundaries from sorted batch.
// ---------------------------------------------------------------------------
__global__ __launch_bounds__(256) void seg_bounds_kernel(
    const int* __restrict__ batch, int* __restrict__ seg_start, int n) {
  int i = blockIdx.x * 256 + threadIdx.x;
  if (i >= n) return;
  int a = batch[i];
  int b = (i + 1 < n) ? batch[i + 1] : NG;
  for (int g = a + 1; g <= b; ++g) seg_start[g] = i + 1;
  if (i == 0) for (int g = 0; g <= a; ++g) seg_start[g] = 0;
}

// ---------------------------------------------------------------------------
// One 32(dims)x32(nodes) slice over K=256: 16 MFMAs, W-frags streamed from L2,
// x/oa B-frags persistent in registers.
// ---------------------------------------------------------------------------
__device__ __forceinline__ f32x16 gemm32(const bf16x8 xb[16],
    const unsigned short* __restrict__ Wall, int slice, int lane) {
  const unsigned short* wp = Wall + slice * 8192 + lane * 8;
  f32x16 acc = {0.f, 0.f, 0.f, 0.f, 0.f, 0.f, 0.f, 0.f,
                0.f, 0.f, 0.f, 0.f, 0.f, 0.f, 0.f, 0.f};
#pragma unroll
  for (int ks = 0; ks < 16; ++ks) {
    bf16x8 af = *reinterpret_cast<const bf16x8*>(wp + ks * 512);
    acc = __builtin_amdgcn_mfma_f32_32x32x16_bf16(af, xb[ks], acc, 0, 0, 0);
  }
  return acc;
}

// ---------------------------------------------------------------------------
// K2: fused QKV + scores.  One wave per 32 nodes; zero LDS, zero barriers.
//  D layout (verified): col=lane&31 (node), row=(reg&3)+8*(reg>>2)+4*(lane>>5).
//  v -> global row-major bf16 (8B packed stores); k kept packed bf16 in regs;
//  q folded against k in-lane; shfl_xor(32) completes the 64-dim dot.
// ---------------------------------------------------------------------------
__global__ __launch_bounds__(64, 2) void qkv_scores_kernel(
    const float* __restrict__ x, const unsigned short* __restrict__ Wall,
    const float* __restrict__ bq, const float* __restrict__ bk,
    const float* __restrict__ bv,
    unsigned short* __restrict__ v_out,   // [NN][256] bf16
    float* __restrict__ scores) {         // [NN][16]
  const int lane = threadIdx.x;
  const int col = lane & 31, hi5 = lane >> 5;
  const int n = blockIdx.x * 32 + col;

  // ---- B-frags: x^T, persistent (64 VGPR). frag kb: k = kb*16+hi5*8+j ----
  bf16x8 xb[16];
#pragma unroll
  for (int kb = 0; kb < 16; ++kb) {
    const float* px = x + (size_t)n * CC + kb * 16 + hi5 * 8;
    float4 a0 = *reinterpret_cast<const float4*>(px);
    float4 a1 = *reinterpret_cast<const float4*>(px + 4);
    uint4 u = {pack2(a0.x, a0.y), pack2(a0.z, a0.w),
               pack2(a1.x, a1.y), pack2(a1.z, a1.w)};
    xb[kb] = *reinterpret_cast<bf16x8*>(&u);
  }

  // ---- V: slices 0..7 -> packed 8B stores, row-major v_out ----
#pragma unroll 2
  for (int s = 0; s < 8; ++s) {
    f32x16 acc = gemm32(xb, Wall, s, lane);
#pragma unroll
    for (int q = 0; q < 4; ++q) {
      int d0 = s * 32 + q * 8 + hi5 * 4;
      float4 b4 = *reinterpret_cast<const float4*>(bv + d0);
      uint2 pk = {pack2(acc[4 * q] + b4.x, acc[4 * q + 1] + b4.y),
                  pack2(acc[4 * q + 2] + b4.z, acc[4 * q + 3] + b4.w)};
      *reinterpret_cast<uint2*>(v_out + (size_t)n * CC + d0) = pk;
    }
  }

  // ---- K: slices 8..15 -> packed bf16 regs (64 VGPR) ----
  unsigned kp[8][8];
#pragma unroll
  for (int sl = 0; sl < 8; ++sl) {
    f32x16 acc = gemm32(xb, Wall, 8 + sl, lane);
#pragma unroll
    for (int q = 0; q < 4; ++q) {
      float4 b4 = *reinterpret_cast<const float4*>(bk + sl * 32 + q * 8 + hi5 * 4);
      kp[sl][q * 2]     = pack2(acc[4 * q] + b4.x, acc[4 * q + 1] + b4.y);
      kp[sl][q * 2 + 1] = pack2(acc[4 * q + 2] + b4.z, acc[4 * q + 3] + b4.w);
    }
  }

  // ---- Q: slices 16..23, fold against kp in-lane ----
  float sp[16];
#pragma unroll
  for (int i = 0; i < 16; ++i) sp[i] = 0.f;
#pragma unroll
  for (int sq = 0; sq < 8; ++sq) {
    const int h = sq >> 1, p = sq & 1;
    f32x16 acc = gemm32(xb, Wall, 16 + sq, lane);
#pragma unroll
    for (int q = 0; q < 4; ++q) {
      float4 b4 = *reinterpret_cast<const float4*>(bq + sq * 32 + q * 8 + hi5 * 4);
      float q0 = acc[4 * q] + b4.x, q1 = acc[4 * q + 1] + b4.y;
      float q2 = acc[4 * q + 2] + b4.z, q3 = acc[4 * q + 3] + b4.w;
#pragma unroll
      for (int g = 0; g < 4; ++g) {
        unsigned k01 = kp[2 * g + p][q * 2];
        unsigned k23 = kp[2 * g + p][q * 2 + 1];
        sp[h * 4 + g] += q0 * bflo(k01) + q1 * bfhi(k01) +
                         q2 * bflo(k23) + q3 * bfhi(k23);
      }
    }
  }
#pragma unroll
  for (int i = 0; i < 16; ++i) sp[i] += __shfl_xor(sp[i], 32, 64);
  if (hi5 == 0) {
#pragma unroll
    for (int q = 0; q < 4; ++q) {
      float4 o = {sp[q * 4] * 0.125f, sp[q * 4 + 1] * 0.125f,
                  sp[q * 4 + 2] * 0.125f, sp[q * 4 + 3] * 0.125f};
      *reinterpret_cast<float4*>(scores + (size_t)n * 16 + q * 4) = o;
    }
  }
}

// ---------------------------------------------------------------------------
// K3: per-segment max & exp-sum over the 16 score columns (block per segment).
// ---------------------------------------------------------------------------
__global__ __launch_bounds__(256) void seg_softmax_kernel(
    const float* __restrict__ scores, const int* __restrict__ seg_start,
    float* __restrict__ seg_max, float* __restrict__ seg_sum) {
  __shared__ float red[256];
  int g = blockIdx.x;
  int s = seg_start[g], e = seg_start[g + 1];
  int t = threadIdx.x;
  int col = t & 15, sub = t >> 4;

  float m = -INFINITY;
  for (int i = s + sub; i < e; i += 16)
    m = fmaxf(m, scores[(size_t)i * 16 + col]);
  red[t] = m;
  __syncthreads();
  for (int step = 8; step >= 1; step >>= 1) {
    if (sub < step) red[t] = fmaxf(red[t], red[t + step * 16]);
    __syncthreads();
  }
  if (t < 16) seg_max[g * 16 + t] = red[t];
  float mcol = red[col];
  __syncthreads();

  float sum = 0.f;
  for (int i = s + sub; i < e; i += 16)
    sum += expf(scores[(size_t)i * 16 + col] - mcol);
  red[t] = sum;
  __syncthreads();
  for (int step = 8; step >= 1; step >>= 1) {
    if (sub < step) red[t] += red[t + step * 16];
    __syncthreads();
  }
  if (t < 16) seg_sum[g * 16 + t] = red[t];
}

// ---------------------------------------------------------------------------
// K4: fused att + att.v + output GEMM (+bo) + att_mean.  One wave per 32
//     nodes; oa^T B-frags built in-lane; Wo^T slices 24..31 streamed from L2.
// ---------------------------------------------------------------------------
__global__ __launch_bounds__(64, 2) void out_kernel(
    const unsigned short* __restrict__ v_bf, const float* __restrict__ scores,
    const int* __restrict__ batch, const float* __restrict__ seg_max,
    const float* __restrict__ seg_sum, const unsigned short* __restrict__ Wall,
    const float* __restrict__ bo, float* __restrict__ out,
    float* __restrict__ att_mean) {
  const int lane = threadIdx.x;
  const int col = lane & 31, hi5 = lane >> 5;
  const int n = blockIdx.x * 32 + col;

  // ---- att[16] for this lane's node ----
  int b = batch[n];
  float att[16];
#pragma unroll
  for (int q = 0; q < 4; ++q) {
    float4 sc = *reinterpret_cast<const float4*>(scores + (size_t)n * 16 + q * 4);
    float4 mx = *reinterpret_cast<const float4*>(seg_max + b * 16 + q * 4);
    float4 sm = *reinterpret_cast<const float4*>(seg_sum + b * 16 + q * 4);
    att[q * 4 + 0] = expf(sc.x - mx.x) / (sm.x + 1e-16f);
    att[q * 4 + 1] = expf(sc.y - mx.y) / (sm.y + 1e-16f);
    att[q * 4 + 2] = expf(sc.z - mx.z) / (sm.z + 1e-16f);
    att[q * 4 + 3] = expf(sc.w - mx.w) / (sm.w + 1e-16f);
  }
  if (hi5 == 0) {
    float4 am;
    am.x = 0.25f * (att[0] + att[4] + att[8] + att[12]);
    am.y = 0.25f * (att[1] + att[5] + att[9] + att[13]);
    am.z = 0.25f * (att[2] + att[6] + att[10] + att[14]);
    am.w = 0.25f * (att[3] + att[7] + att[11] + att[15]);
    *reinterpret_cast<float4*>(att_mean + (size_t)n * 4) = am;
  }

  // ---- oa^T B-frags: oa[n][h*64+dd] = sum_g att[h*4+g]*v[n][g*64+dd] ----
  bf16x8 oaf[16];
#pragma unroll
  for (int dw = 0; dw < 4; ++dw) {
    int dd = dw * 16 + hi5 * 8;
    float vr[4][8];
#pragma unroll
    for (int g = 0; g < 4; ++g) {
      uint4 vv = *reinterpret_cast<const uint4*>(
          v_bf + (size_t)n * CC + g * 64 + dd);
      vr[g][0] = bflo(vv.x); vr[g][1] = bfhi(vv.x);
      vr[g][2] = bflo(vv.y); vr[g][3] = bfhi(vv.y);
      vr[g][4] = bflo(vv.z); vr[g][5] = bfhi(vv.z);
      vr[g][6] = bflo(vv.w); vr[g][7] = bfhi(vv.w);
    }
#pragma unroll
    for (int h = 0; h < 4; ++h) {
      unsigned res[4];
#pragma unroll
      for (int jj = 0; jj < 4; ++jj) {
        float lo = att[h * 4 + 0] * vr[0][2 * jj] + att[h * 4 + 1] * vr[1][2 * jj] +
                   att[h * 4 + 2] * vr[2][2 * jj] + att[h * 4 + 3] * vr[3][2 * jj];
        float hf = att[h * 4 + 0] * vr[0][2 * jj + 1] + att[h * 4 + 1] * vr[1][2 * jj + 1] +
                   att[h * 4 + 2] * vr[2][2 * jj + 1] + att[h * 4 + 3] * vr[3][2 * jj + 1];
        res[jj] = pack2(lo, hf);
      }
      uint4 u = {res[0], res[1], res[2], res[3]};
      oaf[h * 4 + dw] = *reinterpret_cast<bf16x8*>(&u);
    }
  }

  // ---- output GEMM: Wo^T slices 24..31; D[c][n]; float4 stores ----
#pragma unroll 2
  for (int s = 0; s < 8; ++s) {
    f32x16 acc = gemm32(oaf, Wall, 24 + s, lane);
#pragma unroll
    for (int q = 0; q < 4; ++q) {
      int c0 = s * 32 + q * 8 + hi5 * 4;
      float4 b4 = *reinterpret_cast<const float4*>(bo + c0);
      float4 o = {acc[4 * q] + b4.x, acc[4 * q + 1] + b4.y,
                  acc[4 * q + 2] + b4.z, acc[4 * q + 3] + b4.w};
      *reinterpret_cast<float4*>(out + (size_t)n * CC + c0) = o;
    }
  }
}

// ---------------------------------------------------------------------------
extern "C" void kernel_launch(void* const* d_in, const int* in_sizes, int n_in,
                              void* d_out, int out_size, void* d_ws, size_t ws_size,
                              hipStream_t stream) {
  const float* x  = (const float*)d_in[0];
  const int* batch = (const int*)d_in[1];
  const float* Wq = (const float*)d_in[2];
  const float* bq = (const float*)d_in[3];
  const float* Wk = (const float*)d_in[4];
  const float* bk = (const float*)d_in[5];
  const float* Wv = (const float*)d_in[6];
  const float* bv = (const float*)d_in[7];
  const float* Wo = (const float*)d_in[8];
  const float* bo = (const float*)d_in[9];

  char* ws = (char*)d_ws;
  unsigned short* Wall = (unsigned short*)ws;                //   524,288 B (32 slices)
  int*   seg_start = (int*)(ws + 524288);                    //     2,052 B
  float* seg_max   = (float*)(ws + 528384);                  //    32,768 B
  float* seg_sum   = (float*)(ws + 561152);                  //    32,768 B
  float* scores    = (float*)(ws + 593920);                  // 12,800,000 B
  unsigned short* v_bf = (unsigned short*)(ws + 13393920);   // 102,400,000 B

  float* out = (float*)d_out;
  float* att_mean = out + (size_t)NN * CC;

  prep_kernel<<<1024, 256, 0, stream>>>(Wq, Wk, Wv, Wo, Wall);
  seg_bounds_kernel<<<(NN + 255) / 256, 256, 0, stream>>>(batch, seg_start, NN);
  qkv_scores_kernel<<<NN / 32, 64, 0, stream>>>(x, Wall, bq, bk, bv, v_bf, scores);
  seg_softmax_kernel<<<NG, 256, 0, stream>>>(scores, seg_start, seg_max, seg_sum);
  out_kernel<<<NN / 32, 64, 0, stream>>>(v_bf, scores, batch, seg_max, seg_sum,
                                         Wall, bo, out, att_mean);
}

// Round 5
// 495.550 us; speedup vs baseline: 1.3190x; 1.3190x over previous
//
#include <hip/hip_runtime.h>

// Problem constants (fixed by the reference)
#define NN 200000   // nodes
#define CC 256      // channels
#define NG 512      // graphs/segments

typedef __attribute__((ext_vector_type(8))) __bf16 bf16x8;
typedef __attribute__((ext_vector_type(16))) float f32x16;

__device__ __forceinline__ unsigned short f2bf(float f) {
  union { float f; unsigned u; } v; v.f = f;
  unsigned u = v.u;
  u += 0x7fffu + ((u >> 16) & 1u);   // RNE
  return (unsigned short)(u >> 16);
}
__device__ __forceinline__ unsigned pack2(float a, float b) {
  return (unsigned)f2bf(a) | ((unsigned)f2bf(b) << 16);
}
__device__ __forceinline__ float bflo(unsigned u){ union{unsigned u; float f;} x; x.u = u << 16; return x.f; }
__device__ __forceinline__ float bfhi(unsigned u){ union{unsigned u; float f;} x; x.u = u & 0xffff0000u; return x.f; }

// ---------------------------------------------------------------------------
// K0: prep all weights into 32x32x16 MFMA *A-operand* fragment order for the
// transposed GEMM  C^T[dim][node] = W^T[dim][k] * x^T[k][node].
//  Wall slice s (16 KB each): A[row r = (s%8)*32 + (l&31)][k = ks*16+(l>>5)*8+j]
//  flat idx = s*8192 + ks*512 + l*8 + j.  Slices: 0-7 Wv, 8-15 Wk, 16-23 Wq,
//  24-31 Wo.
// ---------------------------------------------------------------------------
__global__ __launch_bounds__(256) void prep_kernel(
    const float* __restrict__ Wq, const float* __restrict__ Wk,
    const float* __restrict__ Wv, const float* __restrict__ Wo,
    unsigned short* __restrict__ Wall) {
  int idx = blockIdx.x * 256 + threadIdx.x;     // 0..262143
  int s = idx >> 13;
  int inner = idx & 8191;
  int ks = inner >> 9;
  int l = (inner >> 3) & 63;
  int j = inner & 7;
  int r = l & 31, hi5 = l >> 5;
  int k = ks * 16 + hi5 * 8 + j;
  const float* W;
  int c;
  if (s < 8)       { W = Wv; c = s * 32 + r; }
  else if (s < 16) { W = Wk; c = (s - 8) * 32 + r; }
  else if (s < 24) { W = Wq; c = (s - 16) * 32 + r; }
  else             { W = Wo; c = (s - 24) * 32 + r; }
  Wall[idx] = f2bf(W[k * 256 + c]);
}

// ---------------------------------------------------------------------------
// K1: segment boundaries from sorted batch.
// ---------------------------------------------------------------------------
__global__ __launch_bounds__(256) void seg_bounds_kernel(
    const int* __restrict__ batch, int* __restrict__ seg_start, int n) {
  int i = blockIdx.x * 256 + threadIdx.x;
  if (i >= n) return;
  int a = batch[i];
  int b = (i + 1 < n) ? batch[i + 1] : NG;
  for (int g = a + 1; g <= b; ++g) seg_start[g] = i + 1;
  if (i == 0) for (int g = 0; g <= a; ++g) seg_start[g] = 0;
}

// ---------------------------------------------------------------------------
// One 32(dims)x32(nodes) slice over K=256: 16 MFMAs, W-frags streamed from L2,
// x/oa B-frags persistent in registers.
// ---------------------------------------------------------------------------
__device__ __forceinline__ f32x16 gemm32(const bf16x8 xb[16],
    const unsigned short* __restrict__ Wall, int slice, int lane) {
  const unsigned short* wp = Wall + slice * 8192 + lane * 8;
  f32x16 acc = {0.f, 0.f, 0.f, 0.f, 0.f, 0.f, 0.f, 0.f,
                0.f, 0.f, 0.f, 0.f, 0.f, 0.f, 0.f, 0.f};
#pragma unroll
  for (int ks = 0; ks < 16; ++ks) {
    bf16x8 af = *reinterpret_cast<const bf16x8*>(wp + ks * 512);
    acc = __builtin_amdgcn_mfma_f32_32x32x16_bf16(af, xb[ks], acc, 0, 0, 0);
  }
  return acc;
}

// ---------------------------------------------------------------------------
// K2: fused QKV + scores.  One wave per 32 nodes; zero LDS, zero barriers.
//  D layout (verified R4): col=lane&31 (node), row=(reg&3)+8*(reg>>2)+4*(lane>>5).
//  Spill control: launch_bounds(64,1); slice loops unroll 1; K/Q split by
//  half-head-dim p so only kph[4][8] (32 VGPR) is resident at once.
// ---------------------------------------------------------------------------
__global__ __launch_bounds__(64, 1) void qkv_scores_kernel(
    const float* __restrict__ x, const unsigned short* __restrict__ Wall,
    const float* __restrict__ bq, const float* __restrict__ bk,
    const float* __restrict__ bv,
    unsigned short* __restrict__ v_out,   // [NN][256] bf16
    float* __restrict__ scores) {         // [NN][16]
  const int lane = threadIdx.x;
  const int col = lane & 31, hi5 = lane >> 5;
  const int n = blockIdx.x * 32 + col;

  // ---- B-frags: x^T, persistent (64 VGPR). frag kb: k = kb*16+hi5*8+j ----
  bf16x8 xb[16];
#pragma unroll
  for (int kb = 0; kb < 16; ++kb) {
    const float* px = x + (size_t)n * CC + kb * 16 + hi5 * 8;
    float4 a0 = *reinterpret_cast<const float4*>(px);
    float4 a1 = *reinterpret_cast<const float4*>(px + 4);
    uint4 u = {pack2(a0.x, a0.y), pack2(a0.z, a0.w),
               pack2(a1.x, a1.y), pack2(a1.z, a1.w)};
    xb[kb] = *reinterpret_cast<bf16x8*>(&u);
  }

  // ---- V: slices 0..7 -> packed 8B stores, row-major v_out ----
#pragma unroll 1
  for (int s = 0; s < 8; ++s) {
    f32x16 acc = gemm32(xb, Wall, s, lane);
#pragma unroll
    for (int q = 0; q < 4; ++q) {
      int d0 = s * 32 + q * 8 + hi5 * 4;
      float4 b4 = *reinterpret_cast<const float4*>(bv + d0);
      uint2 pk = {pack2(acc[4 * q] + b4.x, acc[4 * q + 1] + b4.y),
                  pack2(acc[4 * q + 2] + b4.z, acc[4 * q + 3] + b4.w)};
      *reinterpret_cast<uint2*>(v_out + (size_t)n * CC + d0) = pk;
    }
  }

  // ---- scores: K then Q, split by half-head-dim p ----
  float sp[16];
#pragma unroll
  for (int i = 0; i < 16; ++i) sp[i] = 0.f;

#pragma unroll 1
  for (int p = 0; p < 2; ++p) {
    unsigned kph[4][8];        // k, packed bf16, head g, this half (32 VGPR)
#pragma unroll
    for (int g = 0; g < 4; ++g) {
      f32x16 acc = gemm32(xb, Wall, 8 + 2 * g + p, lane);
#pragma unroll
      for (int q = 0; q < 4; ++q) {
        float4 b4 = *reinterpret_cast<const float4*>(
            bk + (2 * g + p) * 32 + q * 8 + hi5 * 4);
        kph[g][q * 2]     = pack2(acc[4 * q] + b4.x, acc[4 * q + 1] + b4.y);
        kph[g][q * 2 + 1] = pack2(acc[4 * q + 2] + b4.z, acc[4 * q + 3] + b4.w);
      }
    }
#pragma unroll
    for (int h = 0; h < 4; ++h) {
      f32x16 acc = gemm32(xb, Wall, 16 + 2 * h + p, lane);
#pragma unroll
      for (int q = 0; q < 4; ++q) {
        float4 b4 = *reinterpret_cast<const float4*>(
            bq + (2 * h + p) * 32 + q * 8 + hi5 * 4);
        float q0 = acc[4 * q] + b4.x, q1 = acc[4 * q + 1] + b4.y;
        float q2 = acc[4 * q + 2] + b4.z, q3 = acc[4 * q + 3] + b4.w;
#pragma unroll
        for (int g = 0; g < 4; ++g) {
          unsigned k01 = kph[g][q * 2];
          unsigned k23 = kph[g][q * 2 + 1];
          sp[h * 4 + g] += q0 * bflo(k01) + q1 * bfhi(k01) +
                           q2 * bflo(k23) + q3 * bfhi(k23);
        }
      }
    }
  }

#pragma unroll
  for (int i = 0; i < 16; ++i) sp[i] += __shfl_xor(sp[i], 32, 64);
  if (hi5 == 0) {
#pragma unroll
    for (int q = 0; q < 4; ++q) {
      float4 o = {sp[q * 4] * 0.125f, sp[q * 4 + 1] * 0.125f,
                  sp[q * 4 + 2] * 0.125f, sp[q * 4 + 3] * 0.125f};
      *reinterpret_cast<float4*>(scores + (size_t)n * 16 + q * 4) = o;
    }
  }
}

// ---------------------------------------------------------------------------
// K3: per-segment max & exp-sum over the 16 score columns (block per segment).
// ---------------------------------------------------------------------------
__global__ __launch_bounds__(256) void seg_softmax_kernel(
    const float* __restrict__ scores, const int* __restrict__ seg_start,
    float* __restrict__ seg_max, float* __restrict__ seg_sum) {
  __shared__ float red[256];
  int g = blockIdx.x;
  int s = seg_start[g], e = seg_start[g + 1];
  int t = threadIdx.x;
  int col = t & 15, sub = t >> 4;

  float m = -INFINITY;
  for (int i = s + sub; i < e; i += 16)
    m = fmaxf(m, scores[(size_t)i * 16 + col]);
  red[t] = m;
  __syncthreads();
  for (int step = 8; step >= 1; step >>= 1) {
    if (sub < step) red[t] = fmaxf(red[t], red[t + step * 16]);
    __syncthreads();
  }
  if (t < 16) seg_max[g * 16 + t] = red[t];
  float mcol = red[col];
  __syncthreads();

  float sum = 0.f;
  for (int i = s + sub; i < e; i += 16)
    sum += expf(scores[(size_t)i * 16 + col] - mcol);
  red[t] = sum;
  __syncthreads();
  for (int step = 8; step >= 1; step >>= 1) {
    if (sub < step) red[t] += red[t + step * 16];
    __syncthreads();
  }
  if (t < 16) seg_sum[g * 16 + t] = red[t];
}

// ---------------------------------------------------------------------------
// K4: fused att + att.v + output GEMM (+bo) + att_mean.  One wave per 32
//     nodes; oa^T B-frags built in-lane; Wo^T slices 24..31 streamed from L2.
// ---------------------------------------------------------------------------
__global__ __launch_bounds__(64, 1) void out_kernel(
    const unsigned short* __restrict__ v_bf, const float* __restrict__ scores,
    const int* __restrict__ batch, const float* __restrict__ seg_max,
    const float* __restrict__ seg_sum, const unsigned short* __restrict__ Wall,
    const float* __restrict__ bo, float* __restrict__ out,
    float* __restrict__ att_mean) {
  const int lane = threadIdx.x;
  const int col = lane & 31, hi5 = lane >> 5;
  const int n = blockIdx.x * 32 + col;

  // ---- att[16] for this lane's node ----
  int b = batch[n];
  float att[16];
#pragma unroll
  for (int q = 0; q < 4; ++q) {
    float4 sc = *reinterpret_cast<const float4*>(scores + (size_t)n * 16 + q * 4);
    float4 mx = *reinterpret_cast<const float4*>(seg_max + b * 16 + q * 4);
    float4 sm = *reinterpret_cast<const float4*>(seg_sum + b * 16 + q * 4);
    att[q * 4 + 0] = expf(sc.x - mx.x) / (sm.x + 1e-16f);
    att[q * 4 + 1] = expf(sc.y - mx.y) / (sm.y + 1e-16f);
    att[q * 4 + 2] = expf(sc.z - mx.z) / (sm.z + 1e-16f);
    att[q * 4 + 3] = expf(sc.w - mx.w) / (sm.w + 1e-16f);
  }
  if (hi5 == 0) {
    float4 am;
    am.x = 0.25f * (att[0] + att[4] + att[8] + att[12]);
    am.y = 0.25f * (att[1] + att[5] + att[9] + att[13]);
    am.z = 0.25f * (att[2] + att[6] + att[10] + att[14]);
    am.w = 0.25f * (att[3] + att[7] + att[11] + att[15]);
    *reinterpret_cast<float4*>(att_mean + (size_t)n * 4) = am;
  }

  // ---- oa^T B-frags: oa[n][h*64+dd] = sum_g att[h*4+g]*v[n][g*64+dd] ----
  bf16x8 oaf[16];
#pragma unroll
  for (int dw = 0; dw < 4; ++dw) {
    int dd = dw * 16 + hi5 * 8;
    float vr[4][8];
#pragma unroll
    for (int g = 0; g < 4; ++g) {
      uint4 vv = *reinterpret_cast<const uint4*>(
          v_bf + (size_t)n * CC + g * 64 + dd);
      vr[g][0] = bflo(vv.x); vr[g][1] = bfhi(vv.x);
      vr[g][2] = bflo(vv.y); vr[g][3] = bfhi(vv.y);
      vr[g][4] = bflo(vv.z); vr[g][5] = bfhi(vv.z);
      vr[g][6] = bflo(vv.w); vr[g][7] = bfhi(vv.w);
    }
#pragma unroll
    for (int h = 0; h < 4; ++h) {
      unsigned res[4];
#pragma unroll
      for (int jj = 0; jj < 4; ++jj) {
        float lo = att[h * 4 + 0] * vr[0][2 * jj] + att[h * 4 + 1] * vr[1][2 * jj] +
                   att[h * 4 + 2] * vr[2][2 * jj] + att[h * 4 + 3] * vr[3][2 * jj];
        float hf = att[h * 4 + 0] * vr[0][2 * jj + 1] + att[h * 4 + 1] * vr[1][2 * jj + 1] +
                   att[h * 4 + 2] * vr[2][2 * jj + 1] + att[h * 4 + 3] * vr[3][2 * jj + 1];
        res[jj] = pack2(lo, hf);
      }
      uint4 u = {res[0], res[1], res[2], res[3]};
      oaf[h * 4 + dw] = *reinterpret_cast<bf16x8*>(&u);
    }
  }

  // ---- output GEMM: Wo^T slices 24..31; D[c][n]; float4 stores ----
#pragma unroll 1
  for (int s = 0; s < 8; ++s) {
    f32x16 acc = gemm32(oaf, Wall, 24 + s, lane);
#pragma unroll
    for (int q = 0; q < 4; ++q) {
      int c0 = s * 32 + q * 8 + hi5 * 4;
      float4 b4 = *reinterpret_cast<const float4*>(bo + c0);
      float4 o = {acc[4 * q] + b4.x, acc[4 * q + 1] + b4.y,
                  acc[4 * q + 2] + b4.z, acc[4 * q + 3] + b4.w};
      *reinterpret_cast<float4*>(out + (size_t)n * CC + c0) = o;
    }
  }
}

// ---------------------------------------------------------------------------
extern "C" void kernel_launch(void* const* d_in, const int* in_sizes, int n_in,
                              void* d_out, int out_size, void* d_ws, size_t ws_size,
                              hipStream_t stream) {
  const float* x  = (const float*)d_in[0];
  const int* batch = (const int*)d_in[1];
  const float* Wq = (const float*)d_in[2];
  const float* bq = (const float*)d_in[3];
  const float* Wk = (const float*)d_in[4];
  const float* bk = (const float*)d_in[5];
  const float* Wv = (const float*)d_in[6];
  const float* bv = (const float*)d_in[7];
  const float* Wo = (const float*)d_in[8];
  const float* bo = (const float*)d_in[9];

  char* ws = (char*)d_ws;
  unsigned short* Wall = (unsigned short*)ws;                //   524,288 B (32 slices)
  int*   seg_start = (int*)(ws + 524288);                    //     2,052 B
  float* seg_max   = (float*)(ws + 528384);                  //    32,768 B
  float* seg_sum   = (float*)(ws + 561152);                  //    32,768 B
  float* scores    = (float*)(ws + 593920);                  // 12,800,000 B
  unsigned short* v_bf = (unsigned short*)(ws + 13393920);   // 102,400,000 B

  float* out = (float*)d_out;
  float* att_mean = out + (size_t)NN * CC;

  prep_kernel<<<1024, 256, 0, stream>>>(Wq, Wk, Wv, Wo, Wall);
  seg_bounds_kernel<<<(NN + 255) / 256, 256, 0, stream>>>(batch, seg_start, NN);
  qkv_scores_kernel<<<NN / 32, 64, 0, stream>>>(x, Wall, bq, bk, bv, v_bf, scores);
  seg_softmax_kernel<<<NG, 256, 0, stream>>>(scores, seg_start, seg_max, seg_sum);
  out_kernel<<<NN / 32, 64, 0, stream>>>(v_bf, scores, batch, seg_max, seg_sum,
                                         Wall, bo, out, att_mean);
}